// Round 22
// baseline (165.272 us; speedup 1.0000x reference)
//
#include <hip/hip_runtime.h>

// Problem constants
#define MM 15   // max_peptide_size
#define RR 64   // aa_rep_size
#define PP 34   // pocket positions
#define FF 9    // filter size
#define AA 20   // alphabet size
#define OW 72   // RR + FF - 1
#define AJ 16   // adj-float row stride in LDS

#define WAVE_SHR1 0x138
// wave_shr1: result[lane] = src[lane-1], lane 0 -> 0 (bound_ctrl)  [verified r16/r21]
__device__ __forceinline__ float dpp_shr1(float x) {
    return __int_as_float(__builtin_amdgcn_update_dpp(
        0, __float_as_int(x), WAVE_SHR1, 0xF, 0xF, true));
}

// One block per sample, 4 waves; wave w owns rows p = w + 4j (j = 0..8).
// Phase B: m-outer, 9 parallel accumulators, gates pre-loaded via broadcast b128.
// Conv o=0..63: DPP H-recurrence (zero LDS). Conv o=64..71: tail buffer in LDS,
// one 64-wide pass per 8 rows (~30 insts / 64 outputs vs 136 for DPP-T).
__global__ __launch_bounds__(256)
void ppc_kernel(const float* __restrict__ pe,      // [B, M, R]
                const int*   __restrict__ idx,     // [B, P]
                const int*   __restrict__ adj,     // [B, P, M]
                const float* __restrict__ kernels, // [A, F]
                float*       __restrict__ out)     // [B, P, OW]
{
    const int b    = blockIdx.x;
    const int t    = threadIdx.x;
    const int lane = t & 63;
    const int w    = t >> 6;

    __shared__ float s_adjf[PP * AJ];      // 544 f (col 15 = 0)
    __shared__ int   s_idx[PP];
    __shared__ float s_tail[4][9][8];      // 288 f: s[56..63] per (wave,row)

    const float* peb  = pe  + (size_t)b * (MM * RR);
    const int*   adjb = adj + (size_t)b * (PP * MM);
    float*       outb = out + (size_t)b * (PP * OW);

    // ---- prologue: pe column (global, coalesced), adj/idx staged via vector path
    float pv[MM];
    #pragma unroll
    for (int m = 0; m < MM; ++m) pv[m] = peb[m * RR + lane];

    #pragma unroll
    for (int k = 0; k < 2; ++k) {
        const int i = t + k * 256;
        if (i < PP * MM) {
            const int p = (unsigned)i / MM, m = i - p * MM;
            s_adjf[p * AJ + m] = (float)adjb[i];
        }
    }
    if (t < PP) {
        s_adjf[t * AJ + 15] = 0.0f;
        s_idx[t] = idx[(size_t)b * PP + t];
    }
    __syncthreads();    // the only block-wide barrier

    // ---- gates into registers: 9 rows x 4 float4 (broadcast b128 reads)
    float4 G[9][4];
    #pragma unroll
    for (int j = 0; j < 9; ++j) {
        const int p = w + 4 * j;
        if (p < PP) {
            const float* g = &s_adjf[p * AJ];
            G[j][0] = *(const float4*)&g[0];
            G[j][1] = *(const float4*)&g[4];
            G[j][2] = *(const float4*)&g[8];
            G[j][3] = *(const float4*)&g[12];   // .w == 0
        } else {
            G[j][0] = G[j][1] = G[j][2] = G[j][3] = make_float4(0.f,0.f,0.f,0.f);
        }
    }

    // ---- Phase B, m-outer: 9 independent accumulator chains (2-cy issue)
    float acc[9] = {0.f,0.f,0.f,0.f,0.f,0.f,0.f,0.f,0.f};
    #pragma unroll
    for (int mc = 0; mc < 4; ++mc) {
        #pragma unroll
        for (int mm = 0; mm < 4; ++mm) {
            const int m = mc * 4 + mm;
            if (m < MM) {
                #pragma unroll
                for (int j = 0; j < 9; ++j) {
                    const float gv = (&G[j][mc].x)[mm];
                    acc[j] = fmaf(gv, pv[m], acc[j]);
                }
            }
        }
    }

    // ---- per row: taps (wave-uniform scalar loads, K$-hot after LDS idx),
    // H-recurrence for o = 0..63, save s[56..63] for the tail pass
    #pragma unroll
    for (int j = 0; j < 9; ++j) {
        const int p = w + 4 * j;
        if (p < PP) {
            const int a = s_idx[p];                 // LDS broadcast
            const float* kb = kernels + a * FF;     // 720 B table: K$-hot
            float kf[FF];
            #pragma unroll
            for (int i = 0; i < FF; ++i) kf[i] = kb[i];

            const float s = acc[j];
            float H = kf[8] * s;
            #pragma unroll
            for (int i = 7; i >= 0; --i)
                H = fmaf(kf[i], s, dpp_shr1(H));
            outb[p * OW + lane] = H;                // 256 B coalesced

            if (lane >= 56) s_tail[w][j][lane - 56] = s;
        }
    }

    asm volatile("s_waitcnt lgkmcnt(0)" ::: "memory");  // own-wave tail writes

    // ---- tail pass A: rows j = 0..7 (always valid: p = w+4j <= 31)
    {
        const int jj = lane >> 3;          // row 0..7
        const int u  = lane & 7;           // tail offset: o = 64+u
        const int p  = w + 4 * jj;
        const float* sv = &s_tail[w][jj][0];
        const float* kb = kernels + s_idx[p] * FF;   // per-lane L1-hot loads
        float acc2 = 0.f;
        #pragma unroll
        for (int i = 1; i <= 8; ++i) {     // term valid iff i > u
            const float kv = kb[i];
            const float svv = sv[(8 + u - i) & 7];   // &7 keeps addr in-row; masked below
            acc2 += (i > u) ? kv * svv : 0.f;
        }
        outb[p * OW + 64 + u] = acc2;
    }
    // ---- tail pass B: row j = 8 (p = w+32, only waves 0/1), lanes 0..7
    {
        const int p = w + 32;
        if (p < PP && lane < 8) {
            const int u = lane;
            const float* sv = &s_tail[w][8][0];
            const float* kb = kernels + s_idx[p] * FF;
            float acc2 = 0.f;
            #pragma unroll
            for (int i = 1; i <= 8; ++i) {
                const float kv = kb[i];
                const float svv = sv[(8 + u - i) & 7];
                acc2 += (i > u) ? kv * svv : 0.f;
            }
            outb[p * OW + 64 + u] = acc2;
        }
    }
}

extern "C" void kernel_launch(void* const* d_in, const int* in_sizes, int n_in,
                              void* d_out, int out_size, void* d_ws, size_t ws_size,
                              hipStream_t stream) {
    const float* pe      = (const float*)d_in[0]; // [B,M,R] f32
    const int*   idx     = (const int*)  d_in[1]; // [B,P]   i32
    const int*   adj     = (const int*)  d_in[2]; // [B,P,M] i32
    const float* kernels = (const float*)d_in[3]; // [A,F]   f32
    float*       out     = (float*)d_out;

    const int B = in_sizes[0] / (MM * RR);
    ppc_kernel<<<B, 256, 0, stream>>>(pe, idx, adj, kernels, out);
}